// Round 12
// baseline (74.625 us; speedup 1.0000x reference)
//
#include <hip/hip_runtime.h>
#include <stdint.h>
#include <stddef.h>

#define DEV __device__ __forceinline__

typedef __attribute__((ext_vector_type(4))) float f32x4;
typedef __attribute__((ext_vector_type(8))) short bf16x8;

union FragU { bf16x8 f; uint32_t u[4]; };

DEV uint32_t pk_bf16(float a, float b) {
  uint32_t d;
  asm("v_cvt_pk_bf16_f32 %0, %1, %2" : "=v"(d) : "v"(a), "v"(b));
  return d;
}

DEV uint16_t f2bf(float x) {  // round-to-nearest-even
  uint32_t u = __float_as_uint(x);
  u += 0x7fffu + ((u >> 16) & 1u);
  return (uint16_t)(u >> 16);
}

// ---------------------------------------------------------------------------
// kAll: ONE pre-pass launch. Grid 161.
//  bid<128  : q/k/vT GEMV, 8 rows/block, weights LDS-transposed (coalesced)
//  bid==128 : Ww1 -> bf16 frag order; Ww2*log2e -> bf16 frag order
//  bid>=129 : 32 self-sufficient stat blocks -> partials Mpart/XPp/SNp;
//             LAST stat block (device-scope atomic; counter pre-zeroed via
//             hipMemsetAsync) assembles a2/be2/PtT from partials (~us).
// ---------------------------------------------------------------------------
__launch_bounds__(256)
__global__ void kAll(const float* __restrict__ cf, const float* __restrict__ pos,
                     const float* __restrict__ Wq, const float* __restrict__ Wk,
                     const float* __restrict__ Wv, const float* __restrict__ bq,
                     const float* __restrict__ bk, const float* __restrict__ bv,
                     const float* __restrict__ Ww1, const float* __restrict__ Ww2,
                     const float* __restrict__ Wp1, const float* __restrict__ g_p,
                     const float* __restrict__ b_p, const float* __restrict__ bp2,
                     const float* __restrict__ g_w, const float* __restrict__ b_w,
                     const float* __restrict__ Wp2,
                     float* __restrict__ qo, float* __restrict__ ko,
                     float* __restrict__ vT, uint16_t* __restrict__ W1bf,
                     uint16_t* __restrict__ W2bf, float* __restrict__ hpa,
                     float* __restrict__ Mpart, float* __restrict__ XPp,
                     float* __restrict__ SNp, unsigned int* __restrict__ counter,
                     float* __restrict__ a2o, float* __restrict__ be2o,
                     float* __restrict__ PtT) {
  const int bid = blockIdx.x, t = threadIdx.x;

  __shared__ __align__(16) float Ush[4160];   // GEMV: W^T staging | stats: U
  __shared__ __align__(16) f32x4 X[512];      // stats: X | GEMV: v transpose buf
  __shared__ float redr[64][4][4];
  __shared__ float mred[256][6];
  __shared__ float mred2[64][6];
  __shared__ float rfin[64][4];
  __shared__ float redn[256][2];
  __shared__ float wred[4][2][9];
  __shared__ float a1L[3];
  __shared__ float MfS[6];
  __shared__ float ShfS[3];
  __shared__ unsigned int isLast;

  if (bid < 128) {
    const int c = t & 63, rr = t >> 6;   // rows rr, rr+4 of this block's 8
    const int r0 = bid * 8;
    float accq[2], acck[2], accv[2];
    for (int m = 0; m < 3; ++m) {
      __syncthreads();
      const float* Wm = (m == 0) ? Wq : ((m == 1) ? Wk : Wv);
      for (int idx = t; idx < 4096; idx += 256)
        Ush[(idx & 63) * 65 + (idx >> 6)] = Wm[idx];  // wlds[kk*65+c] = W[c][kk]
      __syncthreads();
#pragma unroll
      for (int rp = 0; rp < 2; ++rp) {
        const int row = r0 + rr + 4 * rp;
        const float* cfr = cf + (size_t)row * 64;    // wave-uniform
        float a = 0.f;
#pragma unroll 8
        for (int kk = 0; kk < 64; ++kk)
          a = fmaf(cfr[kk], Ush[kk * 65 + c], a);
        if (m == 0) accq[rp] = a;
        else if (m == 1) acck[rp] = a;
        else accv[rp] = a;
      }
    }
#pragma unroll
    for (int rp = 0; rp < 2; ++rp) {
      const int bn = r0 + rr + 4 * rp;
      qo[(size_t)bn * 64 + c] = accq[rp] + bq[c];
      ko[(size_t)bn * 64 + c] = acck[rp] + bk[c];
    }
    float* vb = (float*)X;
    const float bvv = bv[c] + bp2[c];
    vb[c * 12 + rr] = accv[0] + bvv;
    vb[c * 12 + rr + 4] = accv[1] + bvv;
    __syncthreads();
    if (t < 128) {
      const int c2 = t >> 1, hf = t & 1;
      const f32x4 v = *(const f32x4*)(vb + c2 * 12 + 4 * hf);
      *(f32x4*)(vT + ((size_t)(r0 >> 9) * 64 + c2) * 512 + (r0 & 511) + 4 * hf) = v;
    }
  } else if (bid == 128) {
    const float L2E = 1.4426950408889634f;
    for (int idx = t; idx < 8192; idx += 256) {
      const int m = idx >> 12;
      const int r = idx & 4095;
      const int f = r >> 9;
      const int l = (r >> 3) & 63;
      const int e = r & 7;
      const int nt = f >> 1, ks = f & 1, lm = l & 15, lq = l >> 4;
      const int row = 16 * nt + lm, col = 8 * lq + 32 * ks + e;
      const float src = m ? (Ww2[row * 64 + col] * L2E) : Ww1[row * 64 + col];
      (m ? W2bf : W1bf)[r] = f2bf(src);
    }
  } else {
    const int sb = bid - 129;
    const int s = sb >> 4, b = (sb >> 3) & 1, chunk = sb & 7;
    const int r0g = b * 512 + chunk * 64;

    // ---- in-block GEMV: U = (s ? k : q+bp2) for own 64 rows ----
    {
      const int w = t >> 6, c = t & 63;
      const float* wr = (s ? Wk : Wq) + c * 64;
      const float bias = s ? bk[c] : (bq[c] + bp2[c]);
      f32x4 wreg[16];
#pragma unroll
      for (int kv = 0; kv < 16; ++kv) wreg[kv] = *(const f32x4*)(wr + kv * 4);
      for (int m = 0; m < 16; ++m) {
        const int row = w * 16 + m;
        const f32x4* cfr = (const f32x4*)(cf + (size_t)(r0g + row) * 64);
        float a0 = bias, a1v = 0.f, a2v = 0.f, a3v = 0.f;
#pragma unroll
        for (int kv = 0; kv < 16; ++kv) {
          const f32x4 f = cfr[kv];
          a0 = fmaf(f.x, wreg[kv].x, a0);
          a1v = fmaf(f.y, wreg[kv].y, a1v);
          a2v = fmaf(f.z, wreg[kv].z, a2v);
          a3v = fmaf(f.w, wreg[kv].w, a3v);
        }
        Ush[row * 64 + c] = (a0 + a1v) + (a2v + a3v);
      }
    }

    // ---- block-redundant a1 (BN1 analytic) ----
    {
      const int l = t & 63, wid = t >> 6;
      for (int b2 = 0; b2 < 2; ++b2) {
        float s9[9] = {0, 0, 0, 0, 0, 0, 0, 0, 0};
        for (int r = 0; r < 2; ++r) {
          const int row = t + 256 * r;
          const float* p = pos + (size_t)(b2 * 512 + row) * 3;
          const float p0 = p[0], p1 = p[1], p2 = p[2];
          s9[0] += p0; s9[1] += p1; s9[2] += p2;
          s9[3] += p0 * p0; s9[4] += p0 * p1; s9[5] += p0 * p2;
          s9[6] += p1 * p1; s9[7] += p1 * p2; s9[8] += p2 * p2;
        }
#pragma unroll
        for (int a = 0; a < 9; ++a) {
          float v = s9[a];
          v += __shfl_xor(v, 1);  v += __shfl_xor(v, 2);  v += __shfl_xor(v, 4);
          v += __shfl_xor(v, 8);  v += __shfl_xor(v, 16); v += __shfl_xor(v, 32);
          s9[a] = v;
        }
        if (l == 0) {
#pragma unroll
          for (int a = 0; a < 9; ++a) wred[wid][b2][a] = s9[a];
        }
      }
    }
    __syncthreads();
    if (t == 0) {
      float C[6] = {0, 0, 0, 0, 0, 0};
      const float invM = 1.0f / 524288.0f;
      for (int b2 = 0; b2 < 2; ++b2) {
        float acc9[9];
#pragma unroll
        for (int a = 0; a < 9; ++a)
          acc9[a] = wred[0][b2][a] + wred[1][b2][a] + wred[2][b2][a] + wred[3][b2][a];
        C[0] += 1024.f * acc9[3] - 2.f * acc9[0] * acc9[0];
        C[1] += 1024.f * acc9[4] - 2.f * acc9[0] * acc9[1];
        C[2] += 1024.f * acc9[5] - 2.f * acc9[0] * acc9[2];
        C[3] += 1024.f * acc9[6] - 2.f * acc9[1] * acc9[1];
        C[4] += 1024.f * acc9[7] - 2.f * acc9[1] * acc9[2];
        C[5] += 1024.f * acc9[8] - 2.f * acc9[2] * acc9[2];
      }
      for (int a = 0; a < 6; ++a) C[a] *= invM;
      for (int tt = 0; tt < 3; ++tt) {
        const float w0 = Wp1[tt * 3 + 0], w1 = Wp1[tt * 3 + 1], w2 = Wp1[tt * 3 + 2];
        const float var = w0 * w0 * C[0] + w1 * w1 * C[3] + w2 * w2 * C[5]
                        + 2.f * (w0 * w1 * C[1] + w0 * w2 * C[2] + w1 * w2 * C[4]);
        a1L[tt] = g_p[tt] * rsqrtf(var + 1e-5f);
      }
    }
    __syncthreads();

    // ---- X from pos (s0/chunk0 writes hpa) ----
    {
      const float a10 = a1L[0], a11 = a1L[1], a12 = a1L[2];
      const float w00 = Wp1[0], w01 = Wp1[1], w02 = Wp1[2];
      const float w10 = Wp1[3], w11 = Wp1[4], w12 = Wp1[5];
      const float w20 = Wp1[6], w21 = Wp1[7], w22 = Wp1[8];
      for (int r = 0; r < 2; ++r) {
        const int row = t + 256 * r;
        const float* p = pos + (size_t)(b * 512 + row) * 3;
        const float p0 = p[0], p1 = p[1], p2 = p[2];
        f32x4 v;
        v.x = a10 * (w00 * p0 + w01 * p1 + w02 * p2);
        v.y = a11 * (w10 * p0 + w11 * p1 + w12 * p2);
        v.z = a12 * (w20 * p0 + w21 * p1 + w22 * p2);
        v.w = 0.f;
        if (s == 0 && chunk == 0)
          *(f32x4*)(hpa + (size_t)(b * 512 + row) * 4) = v;
        if (s) { v.x = -v.x; v.y = -v.y; v.z = -v.z; }
        X[row] = v;
      }
    }
    __syncthreads();

    // ---- pair loop: complete R/C for own 64 rows ----
    {
      const int al = t >> 2, qr = t & 3;
      const int a = chunk * 64 + al;
      const f32x4 xa = X[a];
      const float base0 = xa.x + b_p[0], base1 = xa.y + b_p[1], base2 = xa.z + b_p[2];
      float r0 = 0, r1 = 0, r2 = 0;
      float m00 = 0, m01 = 0, m02 = 0, m11 = 0, m12 = 0, m22 = 0;
#pragma unroll 8
      for (int jj = qr * 128; jj < qr * 128 + 128; ++jj) {
        const f32x4 xj = X[jj];
        const float h0 = fmaxf(0.f, base0 - xj.x);
        const float h1 = fmaxf(0.f, base1 - xj.y);
        const float h2v = fmaxf(0.f, base2 - xj.z);
        r0 += h0; r1 += h1; r2 += h2v;
        if (s == 0) {
          m00 = fmaf(h0, h0, m00); m01 = fmaf(h0, h1, m01); m02 = fmaf(h0, h2v, m02);
          m11 = fmaf(h1, h1, m11); m12 = fmaf(h1, h2v, m12); m22 = fmaf(h2v, h2v, m22);
        }
      }
      redr[al][qr][0] = r0; redr[al][qr][1] = r1; redr[al][qr][2] = r2; redr[al][qr][3] = 0.f;
      mred[t][0] = m00; mred[t][1] = m01; mred[t][2] = m02;
      mred[t][3] = m11; mred[t][4] = m12; mred[t][5] = m22;
    }
    __syncthreads();

    if (t < 64) {
      float sx = 0, sy = 0, sz = 0;
#pragma unroll
      for (int p = 0; p < 4; ++p) { sx += redr[t][p][0]; sy += redr[t][p][1]; sz += redr[t][p][2]; }
      rfin[t][0] = sx; rfin[t][1] = sy; rfin[t][2] = sz; rfin[t][3] = 0.f;
      if (s == 0) {
#pragma unroll
        for (int cc = 0; cc < 6; ++cc)
          mred2[t][cc] = mred[t][cc] + mred[t + 64][cc] + mred[t + 128][cc] + mred[t + 192][cc];
      }
    }
    __syncthreads();

    // ---- fold partials (indexed sb) ----
    if (s == 0 && t < 6) {
      float m = 0.f;
      for (int p = 0; p < 64; ++p) m += mred2[p][t];
      Mpart[sb * 12 + t] = m;
    }
    if (s == 0 && t >= 64 && t < 67) {
      const int tt = t - 64;
      float v = 0.f;
#pragma unroll 8
      for (int a = 0; a < 64; ++a) v += rfin[a][tt];
      Mpart[sb * 12 + 6 + tt] = v;
    }
    if (t < 192) {
      const int c = t & 63, tt = t >> 6;
      float xp = 0.f;
#pragma unroll 8
      for (int a = 0; a < 64; ++a) xp = fmaf(Ush[a * 64 + c], rfin[a][tt], xp);
      if (s) xp = -xp;
      XPp[((size_t)sb * 3 + tt) * 64 + c] = xp;
    }
    {
      const int c = t & 63, g = t >> 6;
      float su = 0.f, su2 = 0.f;
#pragma unroll
      for (int r = 0; r < 16; ++r) {
        const float v = Ush[(g * 16 + r) * 64 + c];
        su += v;
        su2 = fmaf(v, v, su2);
      }
      redn[t][0] = su; redn[t][1] = su2;
    }
    __syncthreads();
    if (t < 64) {
      float a0 = 0.f, a1v = 0.f;
#pragma unroll
      for (int p = 0; p < 4; ++p) { a0 += redn[t + 64 * p][0]; a1v += redn[t + 64 * p][1]; }
      SNp[((size_t)sb * 2 + 0) * 64 + t] = a0;
      SNp[((size_t)sb * 2 + 1) * 64 + t] = a1v;
    }

    // ---- completion: last stat block assembles from partials only ----
    __syncthreads();
    if (t == 0) {
      __threadfence();
      const unsigned int old = atomicAdd(counter, 1u);
      isLast = (old == 31u) ? 1u : 0u;
    }
    __syncthreads();
    if (isLast) {
      __threadfence();
      if (t < 6) {
        float m = 0.f;
#pragma unroll
        for (int p = 0; p < 16; ++p) m += Mpart[p * 12 + t];
        MfS[t] = m;
      }
      if (t >= 6 && t < 9) {
        const int tt = t - 6;
        float v = 0.f;
#pragma unroll
        for (int p = 0; p < 16; ++p) v += Mpart[p * 12 + 6 + tt];
        ShfS[tt] = v;
      }
      __syncthreads();
      if (t < 64) {
        const int c = t;
        float Su[2], Su2[2], Sk[2], Sk2[2];
#pragma unroll
        for (int bb = 0; bb < 2; ++bb) {
          float a0 = 0.f, a1v = 0.f, a2v = 0.f, a3 = 0.f;
#pragma unroll
          for (int p = 0; p < 8; ++p) {
            const int blkU = bb * 8 + p;
            const int blkK = 16 + bb * 8 + p;
            a0 += SNp[((size_t)blkU * 2 + 0) * 64 + c];
            a1v += SNp[((size_t)blkU * 2 + 1) * 64 + c];
            a2v += SNp[((size_t)blkK * 2 + 0) * 64 + c];
            a3 += SNp[((size_t)blkK * 2 + 1) * 64 + c];
          }
          Su[bb] = a0; Su2[bb] = a1v; Sk[bb] = a2v; Sk2[bb] = a3;
        }
        float URd0 = 0.f, URd1 = 0.f, URd2 = 0.f;
#pragma unroll
        for (int blk = 0; blk < 32; ++blk) {
          URd0 += XPp[((size_t)blk * 3 + 0) * 64 + c];
          URd1 += XPp[((size_t)blk * 3 + 1) * 64 + c];
          URd2 += XPp[((size_t)blk * 3 + 2) * 64 + c];
        }
        const float P0t = Wp2[c * 3 + 0], P1t = Wp2[c * 3 + 1], P2t = Wp2[c * 3 + 2];
        const float Nf = 512.f, invM = 1.f / 524288.f;
        float S1 = 0.f, Q2 = 0.f;
#pragma unroll
        for (int bb = 0; bb < 2; ++bb) {
          S1 += Nf * (Su[bb] - Sk[bb]);
          Q2 += Nf * Su2[bb] - 2.f * Su[bb] * Sk[bb] + Nf * Sk2[bb];
        }
        const float Xc = P0t * URd0 + P1t * URd1 + P2t * URd2;
        S1 += P0t * ShfS[0] + P1t * ShfS[1] + P2t * ShfS[2];
        const float Hm = P0t * P0t * MfS[0] + 2.f * P0t * P1t * MfS[1] + 2.f * P0t * P2t * MfS[2]
                       + P1t * P1t * MfS[3] + 2.f * P1t * P2t * MfS[4] + P2t * P2t * MfS[5];
        const float E1 = S1 * invM;
        const float E2 = (Q2 + 2.f * Xc + Hm) * invM;
        const float var = E2 - E1 * E1;
        const float rstd = rsqrtf(var + 1e-5f);
        const float A2 = g_w[c] * rstd;
        a2o[c] = A2;
        be2o[c] = b_w[c] - E1 * A2;
        PtT[0 * 64 + c] = A2 * P0t;
        PtT[1 * 64 + c] = A2 * P1t;
        PtT[2 * 64 + c] = A2 * P2t;
      }
    }
  }
}

// ---------------------------------------------------------------------------
// k3: round-7 validated kernel (45.3 us): bf16, kv prefetch, C-init biases,
// exp2-direct, no setprio, reads a2/be2/PtT directly.
// ---------------------------------------------------------------------------
__launch_bounds__(256)
__global__ void k3_main(const float* __restrict__ q, const float* __restrict__ kk_,
                        const float* __restrict__ vT, const float* __restrict__ hpa,
                        const float* __restrict__ a2g, const float* __restrict__ be2g,
                        const float* __restrict__ PtTg,
                        const uint16_t* __restrict__ W1bf, const uint16_t* __restrict__ W2bf,
                        const float* __restrict__ bp2, const float* __restrict__ Wp2,
                        const float* __restrict__ b_p, const float* __restrict__ bw1g,
                        const float* __restrict__ bw2g, float* __restrict__ out) {
  const int bid = blockIdx.x;
  const int b = bid >> 9, i = bid & 511;
  const int t = threadIdx.x;
  const int wid = t >> 6, l = t & 63;
  const int lm = l & 15, lq = l >> 4;

  __shared__ __align__(16) uint16_t W1l[4096];
  __shared__ __align__(16) uint16_t W2l[4096];
  __shared__ __align__(16) uint16_t H2[4][16][76];
  __shared__ __align__(16) float P0[64];
  __shared__ __align__(16) float a2s[64];
  __shared__ __align__(16) float Pts[3][64];
  __shared__ __align__(16) float comb[4][64][2];

  {
    *(bf16x8*)(&W1l[t * 16])     = *(const bf16x8*)(W1bf + t * 16);
    *(bf16x8*)(&W1l[t * 16 + 8]) = *(const bf16x8*)(W1bf + t * 16 + 8);
    *(bf16x8*)(&W2l[t * 16])     = *(const bf16x8*)(W2bf + t * 16);
    *(bf16x8*)(&W2l[t * 16 + 8]) = *(const bf16x8*)(W2bf + t * 16 + 8);
  }
  if (t < 64) {
    const float a2v = a2g[t];
    a2s[t] = a2v;
    P0[t] = fmaf(a2v, q[(size_t)(b * 512 + i) * 64 + t] + bp2[t], be2g[t]);
  } else {
    const int idx = t - 64;
    if (idx < 192) Pts[idx >> 6][idx & 63] = PtTg[idx];
  }

  const f32x4 hi = *(const f32x4*)(hpa + (size_t)(b * 512 + i) * 4);
  const float bb0 = b_p[0], bb1 = b_p[1], bb2 = b_p[2];
  const float LOG2E = 1.4426950408889634f;

  float bw1r[4], bw2l[4], wpa[4], wpb[4], wpc[4];
#pragma unroll
  for (int nt = 0; nt < 4; ++nt) {
    const int c = 16 * nt + lm;
    bw1r[nt] = bw1g[c];
    bw2l[nt] = bw2g[c] * LOG2E;
    wpa[nt] = Wp2[c * 3 + 0];
    wpb[nt] = Wp2[c * 3 + 1];
    wpc[nt] = Wp2[c * 3 + 2];
  }

  float l_[4] = {0.f, 0.f, 0.f, 0.f};
  float acc_[4] = {0.f, 0.f, 0.f, 0.f};

  __syncthreads();

  const float* kbase = kk_ + (size_t)(b * 512) * 64;
  const float* hbase = hpa + (size_t)(b * 512) * 4;
  const float* vTb = vT + (size_t)b * 64 * 512;

  // prefetch k-row for it=0
  f32x4 kvA[2][2];
  {
    const int j0 = wid * 16 + lm;
#pragma unroll
    for (int ks = 0; ks < 2; ++ks) {
      kvA[ks][0] = *(const f32x4*)(kbase + (size_t)j0 * 64 + 32 * ks + 8 * lq);
      kvA[ks][1] = *(const f32x4*)(kbase + (size_t)j0 * 64 + 32 * ks + 8 * lq + 4);
    }
  }

  for (int it = 0; it < 8; ++it) {
    const int jb = it * 64 + wid * 16;
    const int j = jb + lm;
    const int j2 = jb + 4 * lq;

    f32x4 kvN[2][2];
    if (it < 7) {
      const int jn = j + 64;
#pragma unroll
      for (int ks = 0; ks < 2; ++ks) {
        kvN[ks][0] = *(const f32x4*)(kbase + (size_t)jn * 64 + 32 * ks + 8 * lq);
        kvN[ks][1] = *(const f32x4*)(kbase + (size_t)jn * 64 + 32 * ks + 8 * lq + 4);
      }
    }

    const f32x4 hj = *(const f32x4*)(hbase + j * 4);
    f32x4 hjr[4];
#pragma unroll
    for (int r = 0; r < 4; ++r) hjr[r] = *(const f32x4*)(hbase + (j2 + r) * 4);
    f32x4 vv[4];
#pragma unroll
    for (int nt = 0; nt < 4; ++nt)
      vv[nt] = *(const f32x4*)(vTb + (size_t)(16 * nt + lm) * 512 + j2);

    // ---- stage A: x = relu(a2*qk + b2) as A-fragments ----
    const float h0 = fmaxf(0.f, hi.x - hj.x + bb0);
    const float h1 = fmaxf(0.f, hi.y - hj.y + bb1);
    const float h2v = fmaxf(0.f, hi.z - hj.z + bb2);

    FragU A1[2];
#pragma unroll
    for (int ks = 0; ks < 2; ++ks) {
      const int c0 = 32 * ks + 8 * lq;
      f32x4 pv[2], av[2], t0[2], t1[2], t2[2];
      pv[0] = *(const f32x4*)(P0 + c0);        pv[1] = *(const f32x4*)(P0 + c0 + 4);
      av[0] = *(const f32x4*)(a2s + c0);       av[1] = *(const f32x4*)(a2s + c0 + 4);
      t0[0] = *(const f32x4*)(&Pts[0][c0]);    t0[1] = *(const f32x4*)(&Pts[0][c0 + 4]);
      t1[0] = *(const f32x4*)(&Pts[1][c0]);    t1[1] = *(const f32x4*)(&Pts[1][c0 + 4]);
      t2[0] = *(const f32x4*)(&Pts[2][c0]);    t2[1] = *(const f32x4*)(&Pts[2][c0 + 4]);
      float x[8];
#pragma unroll
      for (int e = 0; e < 8; ++e) {
        const int hh = e >> 2, e4 = e & 3;
        float xv = pv[hh][e4] - av[hh][e4] * kvA[ks][hh][e4];
        xv = fmaf(t0[hh][e4], h0, xv);
        xv = fmaf(t1[hh][e4], h1, xv);
        xv = fmaf(t2[hh][e4], h2v, xv);
        x[e] = fmaxf(0.f, xv);
      }
      A1[ks].u[0] = pk_bf16(x[0], x[1]);
      A1[ks].u[1] = pk_bf16(x[2], x[3]);
      A1[ks].u[2] = pk_bf16(x[4], x[5]);
      A1[ks].u[3] = pk_bf16(x[6], x[7]);
    }

    // ---- GEMM1 (bias in C-init) ----
    f32x4 d1[4];
#pragma unroll
    for (int nt = 0; nt < 4; ++nt) {
      FragU b0, b1;
      b0.f = *(const bf16x8*)(&W1l[((nt * 2 + 0) * 64 + l) * 8]);
      b1.f = *(const bf16x8*)(&W1l[((nt * 2 + 1) * 64 + l) * 8]);
      f32x4 z = {bw1r[nt], bw1r[nt], bw1r[nt], bw1r[nt]};
      z = __builtin_amdgcn_mfma_f32_16x16x32_bf16(A1[0].f, b0.f, z, 0, 0, 0);
      z = __builtin_amdgcn_mfma_f32_16x16x32_bf16(A1[1].f, b1.f, z, 0, 0, 0);
      d1[nt] = z;
    }

    // ---- relu, repack h2 to bf16 LDS (per-wave private, pad 76) ----
    uint16_t (*h2w)[76] = H2[wid];
#pragma unroll
    for (int nt = 0; nt < 4; ++nt) {
      const uint32_t u01 = pk_bf16(fmaxf(0.f, d1[nt][0]), fmaxf(0.f, d1[nt][1]));
      const uint32_t u23 = pk_bf16(fmaxf(0.f, d1[nt][2]), fmaxf(0.f, d1[nt][3]));
      const int col = 16 * nt + lm;
      h2w[4 * lq + 0][col] = (uint16_t)(u01 & 0xffffu);
      h2w[4 * lq + 1][col] = (uint16_t)(u01 >> 16);
      h2w[4 * lq + 2][col] = (uint16_t)(u23 & 0xffffu);
      h2w[4 * lq + 3][col] = (uint16_t)(u23 >> 16);
    }

    FragU A2[2];
    A2[0].f = *(const bf16x8*)(&h2w[lm][8 * lq]);
    A2[1].f = *(const bf16x8*)(&h2w[lm][32 + 8 * lq]);

    // ---- GEMM2 (log2e-scaled W2, bias*log2e in C-init) ----
    f32x4 d2[4];
#pragma unroll
    for (int nt = 0; nt < 4; ++nt) {
      FragU b0, b1;
      b0.f = *(const bf16x8*)(&W2l[((nt * 2 + 0) * 64 + l) * 8]);
      b1.f = *(const bf16x8*)(&W2l[((nt * 2 + 1) * 64 + l) * 8]);
      f32x4 z = {bw2l[nt], bw2l[nt], bw2l[nt], bw2l[nt]};
      z = __builtin_amdgcn_mfma_f32_16x16x32_bf16(A2[0].f, b0.f, z, 0, 0, 0);
      z = __builtin_amdgcn_mfma_f32_16x16x32_bf16(A2[1].f, b1.f, z, 0, 0, 0);
      d2[nt] = z;
    }

    // ---- hr for this lane's 4 output j-rows ----
    float hr0[4], hr1[4], hr2[4];
#pragma unroll
    for (int r = 0; r < 4; ++r) {
      hr0[r] = fmaxf(0.f, hi.x - hjr[r].x + bb0);
      hr1[r] = fmaxf(0.f, hi.y - hjr[r].y + bb1);
      hr2[r] = fmaxf(0.f, hi.z - hjr[r].z + bb2);
    }

    // ---- no-max softmax accumulation (exp2 direct) ----
#pragma unroll
    for (int nt = 0; nt < 4; ++nt) {
      float p[4], val[4];
#pragma unroll
      for (int r = 0; r < 4; ++r) {
        p[r] = __builtin_amdgcn_exp2f(d2[nt][r]);
        float v0 = vv[nt][r];
        v0 = fmaf(wpa[nt], hr0[r], v0);
        v0 = fmaf(wpb[nt], hr1[r], v0);
        v0 = fmaf(wpc[nt], hr2[r], v0);
        val[r] = v0;
      }
      l_[nt] += (p[0] + p[1]) + (p[2] + p[3]);
      float a = acc_[nt];
      a = fmaf(p[0], val[0], a);
      a = fmaf(p[1], val[1], a);
      a = fmaf(p[2], val[2], a);
      a = fmaf(p[3], val[3], a);
      acc_[nt] = a;
    }

    // rotate prefetch
    if (it < 7) {
#pragma unroll
      for (int ks = 0; ks < 2; ++ks) {
        kvA[ks][0] = kvN[ks][0];
        kvA[ks][1] = kvN[ks][1];
      }
    }
  }

  // ---- combine (linear): shfl over lq groups, then across waves ----
#pragma unroll
  for (int nt = 0; nt < 4; ++nt) {
    l_[nt] += __shfl_xor(l_[nt], 16);
    acc_[nt] += __shfl_xor(acc_[nt], 16);
    l_[nt] += __shfl_xor(l_[nt], 32);
    acc_[nt] += __shfl_xor(acc_[nt], 32);
  }
  if (lq == 0) {
#pragma unroll
    for (int nt = 0; nt < 4; ++nt) {
      comb[wid][16 * nt + lm][0] = l_[nt];
      comb[wid][16 * nt + lm][1] = acc_[nt];
    }
  }
  __syncthreads();
  if (t < 64) {
    float L = 0.f, A = 0.f;
#pragma unroll
    for (int w = 0; w < 4; ++w) {
      L += comb[w][t][0];
      A += comb[w][t][1];
    }
    out[(size_t)(b * 512 + i) * 64 + t] = A / L;
  }
}

// ---------------------------------------------------------------------------
extern "C" void kernel_launch(void* const* d_in, const int* in_sizes, int n_in,
                              void* d_out, int out_size, void* d_ws, size_t ws_size,
                              hipStream_t stream) {
  (void)in_sizes; (void)n_in; (void)out_size; (void)ws_size;
  const float* pos = (const float*)d_in[0];
  const float* cf  = (const float*)d_in[1];
  const float* Wq  = (const float*)d_in[2];
  const float* bq  = (const float*)d_in[3];
  const float* Wk  = (const float*)d_in[4];
  const float* bk  = (const float*)d_in[5];
  const float* Wv  = (const float*)d_in[6];
  const float* bv  = (const float*)d_in[7];
  const float* Wp1 = (const float*)d_in[8];
  // d_in[9] = bp1: cancels analytically (gamma1 == b_p exactly)
  const float* g_p = (const float*)d_in[10];
  const float* b_p = (const float*)d_in[11];
  const float* Wp2 = (const float*)d_in[12];
  const float* bp2 = (const float*)d_in[13];
  const float* g_w = (const float*)d_in[14];
  const float* b_w = (const float*)d_in[15];
  const float* Ww1 = (const float*)d_in[16];
  const float* bw1 = (const float*)d_in[17];
  const float* Ww2 = (const float*)d_in[18];
  const float* bw2 = (const float*)d_in[19];

  char* ws = (char*)d_ws;
  uint16_t*     W1bf = (uint16_t*)(ws + 0);        // 8 KB
  uint16_t*     W2bf = (uint16_t*)(ws + 8192);     // 8 KB (log2e-scaled)
  unsigned int* cnt  = (unsigned int*)(ws + 16384);
  float*        hpaw = (float*)(ws + 16896);       // [1024][4]
  float*        qw   = (float*)(ws + 33280);       // [1024][64]
  float*        kw   = (float*)(ws + 295424);      // [1024][64]
  float*        vTw  = (float*)(ws + 557568);      // [2][64][512]
  float*        a2w  = (float*)(ws + 819712);
  float*        be2w = (float*)(ws + 819968);
  float*        PtTw = (float*)(ws + 820224);      // [3][64]
  float*        Mpw  = (float*)(ws + 821248);      // [32][12]
  float*        XPpw = (float*)(ws + 823040);      // [32][3][64]
  float*        SNpw = (float*)(ws + 847872);      // [32][2][64]

  hipMemsetAsync(cnt, 0, sizeof(unsigned int), stream);
  kAll<<<dim3(161), dim3(256), 0, stream>>>(cf, pos, Wq, Wk, Wv, bq, bk, bv,
                                            Ww1, Ww2, Wp1, g_p, b_p, bp2,
                                            g_w, b_w, Wp2,
                                            qw, kw, vTw, W1bf, W2bf, hpaw,
                                            Mpw, XPpw, SNpw, cnt,
                                            a2w, be2w, PtTw);
  k3_main<<<dim3(1024), dim3(256), 0, stream>>>(qw, kw, vTw, hpaw, a2w, be2w, PtTw,
                                                W1bf, W2bf, bp2, Wp2, b_p, bw1, bw2,
                                                (float*)d_out);
}

// Round 13
// 69.410 us; speedup vs baseline: 1.0751x; 1.0751x over previous
//
#include <hip/hip_runtime.h>
#include <stdint.h>
#include <stddef.h>

#define DEV __device__ __forceinline__

typedef __attribute__((ext_vector_type(4))) float f32x4;
typedef __attribute__((ext_vector_type(8))) short bf16x8;

union FragU { bf16x8 f; uint32_t u[4]; };

DEV uint32_t pk_bf16(float a, float b) {
  uint32_t d;
  asm("v_cvt_pk_bf16_f32 %0, %1, %2" : "=v"(d) : "v"(a), "v"(b));
  return d;
}

DEV uint16_t f2bf(float x) {  // round-to-nearest-even
  uint32_t u = __float_as_uint(x);
  u += 0x7fffu + ((u >> 16) & 1u);
  return (uint16_t)(u >> 16);
}

// ---------------------------------------------------------------------------
// kAll: ONE pre-pass launch, no atomics. Grid 161.
//  bid<128  : q/k/vT GEMV, 8 rows/block, weights LDS-transposed, 4-acc ILP
//  bid==128 : Ww1 -> bf16 frag order; Ww2*log2e -> bf16 frag order
//  bid>=129 : 32 self-sufficient stat blocks -> partials Mpart/XPp/SNp
// ---------------------------------------------------------------------------
__launch_bounds__(256)
__global__ void kAll(const float* __restrict__ cf, const float* __restrict__ pos,
                     const float* __restrict__ Wq, const float* __restrict__ Wk,
                     const float* __restrict__ Wv, const float* __restrict__ bq,
                     const float* __restrict__ bk, const float* __restrict__ bv,
                     const float* __restrict__ Ww1, const float* __restrict__ Ww2,
                     const float* __restrict__ Wp1, const float* __restrict__ g_p,
                     const float* __restrict__ b_p, const float* __restrict__ bp2,
                     float* __restrict__ qo, float* __restrict__ ko,
                     float* __restrict__ vT, uint16_t* __restrict__ W1bf,
                     uint16_t* __restrict__ W2bf, float* __restrict__ hpa,
                     float* __restrict__ Mpart, float* __restrict__ XPp,
                     float* __restrict__ SNp) {
  const int bid = blockIdx.x, t = threadIdx.x;

  __shared__ __align__(16) float Ush[4160];   // GEMV: W^T staging | stats: U
  __shared__ __align__(16) f32x4 X[512];      // stats: X | GEMV: v transpose buf
  __shared__ float redr[64][4][4];
  __shared__ float mred[256][6];
  __shared__ float mred2[64][6];
  __shared__ float rfin[64][4];
  __shared__ float redn[256][2];
  __shared__ float wred[4][2][9];
  __shared__ float a1L[3];

  if (bid < 128) {
    const int c = t & 63, rr = t >> 6;   // rows rr, rr+4 of this block's 8
    const int r0 = bid * 8;
    float accq[2], acck[2], accv[2];
    for (int m = 0; m < 3; ++m) {
      __syncthreads();
      const float* Wm = (m == 0) ? Wq : ((m == 1) ? Wk : Wv);
      for (int idx = t; idx < 4096; idx += 256)
        Ush[(idx & 63) * 65 + (idx >> 6)] = Wm[idx];  // wlds[kk*65+c] = W[c][kk]
      __syncthreads();
#pragma unroll
      for (int rp = 0; rp < 2; ++rp) {
        const int row = r0 + rr + 4 * rp;
        const float* cfr = cf + (size_t)row * 64;    // wave-uniform
        float a0 = 0.f, a1 = 0.f, a2 = 0.f, a3 = 0.f;   // 4-chain ILP
#pragma unroll 4
        for (int kk = 0; kk < 64; kk += 4) {
          a0 = fmaf(cfr[kk + 0], Ush[(kk + 0) * 65 + c], a0);
          a1 = fmaf(cfr[kk + 1], Ush[(kk + 1) * 65 + c], a1);
          a2 = fmaf(cfr[kk + 2], Ush[(kk + 2) * 65 + c], a2);
          a3 = fmaf(cfr[kk + 3], Ush[(kk + 3) * 65 + c], a3);
        }
        const float a = (a0 + a1) + (a2 + a3);
        if (m == 0) accq[rp] = a;
        else if (m == 1) acck[rp] = a;
        else accv[rp] = a;
      }
    }
#pragma unroll
    for (int rp = 0; rp < 2; ++rp) {
      const int bn = r0 + rr + 4 * rp;
      qo[(size_t)bn * 64 + c] = accq[rp] + bq[c];
      ko[(size_t)bn * 64 + c] = acck[rp] + bk[c];
    }
    float* vb = (float*)X;                 // stride 12: 16B-aligned f32x4 reads
    const float bvv = bv[c] + bp2[c];
    vb[c * 12 + rr] = accv[0] + bvv;
    vb[c * 12 + rr + 4] = accv[1] + bvv;
    __syncthreads();
    if (t < 128) {
      const int c2 = t >> 1, hf = t & 1;
      const f32x4 v = *(const f32x4*)(vb + c2 * 12 + 4 * hf);
      *(f32x4*)(vT + ((size_t)(r0 >> 9) * 64 + c2) * 512 + (r0 & 511) + 4 * hf) = v;
    }
  } else if (bid == 128) {
    const float L2E = 1.4426950408889634f;
    for (int idx = t; idx < 8192; idx += 256) {
      const int m = idx >> 12;
      const int r = idx & 4095;
      const int f = r >> 9;
      const int l = (r >> 3) & 63;
      const int e = r & 7;
      const int nt = f >> 1, ks = f & 1, lm = l & 15, lq = l >> 4;
      const int row = 16 * nt + lm, col = 8 * lq + 32 * ks + e;
      const float src = m ? (Ww2[row * 64 + col] * L2E) : Ww1[row * 64 + col];
      (m ? W2bf : W1bf)[r] = f2bf(src);
    }
  } else {
    const int sb = bid - 129;
    const int s = sb >> 4, b = (sb >> 3) & 1, chunk = sb & 7;
    const int r0g = b * 512 + chunk * 64;

    // ---- in-block GEMV: U = (s ? k : q+bp2) for own 64 rows ----
    {
      const int w = t >> 6, c = t & 63;
      const float* wr = (s ? Wk : Wq) + c * 64;
      const float bias = s ? bk[c] : (bq[c] + bp2[c]);
      f32x4 wreg[16];
#pragma unroll
      for (int kv = 0; kv < 16; ++kv) wreg[kv] = *(const f32x4*)(wr + kv * 4);
      for (int m = 0; m < 16; ++m) {
        const int row = w * 16 + m;
        const f32x4* cfr = (const f32x4*)(cf + (size_t)(r0g + row) * 64);
        float a0 = bias, a1v = 0.f, a2v = 0.f, a3v = 0.f;
#pragma unroll
        for (int kv = 0; kv < 16; ++kv) {
          const f32x4 f = cfr[kv];
          a0 = fmaf(f.x, wreg[kv].x, a0);
          a1v = fmaf(f.y, wreg[kv].y, a1v);
          a2v = fmaf(f.z, wreg[kv].z, a2v);
          a3v = fmaf(f.w, wreg[kv].w, a3v);
        }
        Ush[row * 64 + c] = (a0 + a1v) + (a2v + a3v);
      }
    }

    // ---- block-redundant a1 (BN1 analytic) ----
    {
      const int l = t & 63, wid = t >> 6;
      for (int b2 = 0; b2 < 2; ++b2) {
        float s9[9] = {0, 0, 0, 0, 0, 0, 0, 0, 0};
        for (int r = 0; r < 2; ++r) {
          const int row = t + 256 * r;
          const float* p = pos + (size_t)(b2 * 512 + row) * 3;
          const float p0 = p[0], p1 = p[1], p2 = p[2];
          s9[0] += p0; s9[1] += p1; s9[2] += p2;
          s9[3] += p0 * p0; s9[4] += p0 * p1; s9[5] += p0 * p2;
          s9[6] += p1 * p1; s9[7] += p1 * p2; s9[8] += p2 * p2;
        }
#pragma unroll
        for (int a = 0; a < 9; ++a) {
          float v = s9[a];
          v += __shfl_xor(v, 1);  v += __shfl_xor(v, 2);  v += __shfl_xor(v, 4);
          v += __shfl_xor(v, 8);  v += __shfl_xor(v, 16); v += __shfl_xor(v, 32);
          s9[a] = v;
        }
        if (l == 0) {
#pragma unroll
          for (int a = 0; a < 9; ++a) wred[wid][b2][a] = s9[a];
        }
      }
    }
    __syncthreads();
    if (t == 0) {
      float C[6] = {0, 0, 0, 0, 0, 0};
      const float invM = 1.0f / 524288.0f;
      for (int b2 = 0; b2 < 2; ++b2) {
        float acc9[9];
#pragma unroll
        for (int a = 0; a < 9; ++a)
          acc9[a] = wred[0][b2][a] + wred[1][b2][a] + wred[2][b2][a] + wred[3][b2][a];
        C[0] += 1024.f * acc9[3] - 2.f * acc9[0] * acc9[0];
        C[1] += 1024.f * acc9[4] - 2.f * acc9[0] * acc9[1];
        C[2] += 1024.f * acc9[5] - 2.f * acc9[0] * acc9[2];
        C[3] += 1024.f * acc9[6] - 2.f * acc9[1] * acc9[1];
        C[4] += 1024.f * acc9[7] - 2.f * acc9[1] * acc9[2];
        C[5] += 1024.f * acc9[8] - 2.f * acc9[2] * acc9[2];
      }
      for (int a = 0; a < 6; ++a) C[a] *= invM;
      for (int tt = 0; tt < 3; ++tt) {
        const float w0 = Wp1[tt * 3 + 0], w1 = Wp1[tt * 3 + 1], w2 = Wp1[tt * 3 + 2];
        const float var = w0 * w0 * C[0] + w1 * w1 * C[3] + w2 * w2 * C[5]
                        + 2.f * (w0 * w1 * C[1] + w0 * w2 * C[2] + w1 * w2 * C[4]);
        a1L[tt] = g_p[tt] * rsqrtf(var + 1e-5f);
      }
    }
    __syncthreads();

    // ---- X from pos (s0/chunk0 writes hpa) ----
    {
      const float a10 = a1L[0], a11 = a1L[1], a12 = a1L[2];
      const float w00 = Wp1[0], w01 = Wp1[1], w02 = Wp1[2];
      const float w10 = Wp1[3], w11 = Wp1[4], w12 = Wp1[5];
      const float w20 = Wp1[6], w21 = Wp1[7], w22 = Wp1[8];
      for (int r = 0; r < 2; ++r) {
        const int row = t + 256 * r;
        const float* p = pos + (size_t)(b * 512 + row) * 3;
        const float p0 = p[0], p1 = p[1], p2 = p[2];
        f32x4 v;
        v.x = a10 * (w00 * p0 + w01 * p1 + w02 * p2);
        v.y = a11 * (w10 * p0 + w11 * p1 + w12 * p2);
        v.z = a12 * (w20 * p0 + w21 * p1 + w22 * p2);
        v.w = 0.f;
        if (s == 0 && chunk == 0)
          *(f32x4*)(hpa + (size_t)(b * 512 + row) * 4) = v;
        if (s) { v.x = -v.x; v.y = -v.y; v.z = -v.z; }
        X[row] = v;
      }
    }
    __syncthreads();

    // ---- pair loop: complete R/C for own 64 rows ----
    {
      const int al = t >> 2, qr = t & 3;
      const int a = chunk * 64 + al;
      const f32x4 xa = X[a];
      const float base0 = xa.x + b_p[0], base1 = xa.y + b_p[1], base2 = xa.z + b_p[2];
      float r0 = 0, r1 = 0, r2 = 0;
      float m00 = 0, m01 = 0, m02 = 0, m11 = 0, m12 = 0, m22 = 0;
#pragma unroll 8
      for (int jj = qr * 128; jj < qr * 128 + 128; ++jj) {
        const f32x4 xj = X[jj];
        const float h0 = fmaxf(0.f, base0 - xj.x);
        const float h1 = fmaxf(0.f, base1 - xj.y);
        const float h2v = fmaxf(0.f, base2 - xj.z);
        r0 += h0; r1 += h1; r2 += h2v;
        if (s == 0) {
          m00 = fmaf(h0, h0, m00); m01 = fmaf(h0, h1, m01); m02 = fmaf(h0, h2v, m02);
          m11 = fmaf(h1, h1, m11); m12 = fmaf(h1, h2v, m12); m22 = fmaf(h2v, h2v, m22);
        }
      }
      redr[al][qr][0] = r0; redr[al][qr][1] = r1; redr[al][qr][2] = r2; redr[al][qr][3] = 0.f;
      mred[t][0] = m00; mred[t][1] = m01; mred[t][2] = m02;
      mred[t][3] = m11; mred[t][4] = m12; mred[t][5] = m22;
    }
    __syncthreads();

    if (t < 64) {
      float sx = 0, sy = 0, sz = 0;
#pragma unroll
      for (int p = 0; p < 4; ++p) { sx += redr[t][p][0]; sy += redr[t][p][1]; sz += redr[t][p][2]; }
      rfin[t][0] = sx; rfin[t][1] = sy; rfin[t][2] = sz; rfin[t][3] = 0.f;
      if (s == 0) {
#pragma unroll
        for (int cc = 0; cc < 6; ++cc)
          mred2[t][cc] = mred[t][cc] + mred[t + 64][cc] + mred[t + 128][cc] + mred[t + 192][cc];
      }
    }
    __syncthreads();

    // ---- fold partials (indexed sb) ----
    if (s == 0 && t < 6) {
      float m = 0.f;
      for (int p = 0; p < 64; ++p) m += mred2[p][t];
      Mpart[sb * 12 + t] = m;
    }
    if (s == 0 && t >= 64 && t < 67) {
      const int tt = t - 64;
      float v = 0.f;
#pragma unroll 8
      for (int a = 0; a < 64; ++a) v += rfin[a][tt];
      Mpart[sb * 12 + 6 + tt] = v;
    }
    if (t < 192) {
      const int c = t & 63, tt = t >> 6;
      float xp = 0.f;
#pragma unroll 8
      for (int a = 0; a < 64; ++a) xp = fmaf(Ush[a * 64 + c], rfin[a][tt], xp);
      if (s) xp = -xp;
      XPp[((size_t)sb * 3 + tt) * 64 + c] = xp;
    }
    {
      const int c = t & 63, g = t >> 6;
      float su = 0.f, su2 = 0.f;
#pragma unroll
      for (int r = 0; r < 16; ++r) {
        const float v = Ush[(g * 16 + r) * 64 + c];
        su += v;
        su2 = fmaf(v, v, su2);
      }
      redn[t][0] = su; redn[t][1] = su2;
    }
    __syncthreads();
    if (t < 64) {
      float a0 = 0.f, a1v = 0.f;
#pragma unroll
      for (int p = 0; p < 4; ++p) { a0 += redn[t + 64 * p][0]; a1v += redn[t + 64 * p][1]; }
      SNp[((size_t)sb * 2 + 0) * 64 + t] = a0;
      SNp[((size_t)sb * 2 + 1) * 64 + t] = a1v;
    }
  }
}

// ---------------------------------------------------------------------------
// k3: round-8 validated kernel (47.5 us): stats prologue from partials,
// no setprio, bf16, kv prefetch, C-init biases, exp2-direct.
// ---------------------------------------------------------------------------
__launch_bounds__(256)
__global__ void k3_main(const float* __restrict__ q, const float* __restrict__ kk_,
                        const float* __restrict__ vT, const float* __restrict__ hpa,
                        const float* __restrict__ Mpart, const float* __restrict__ XPp,
                        const float* __restrict__ SNp, const float* __restrict__ g_w,
                        const float* __restrict__ b_w,
                        const uint16_t* __restrict__ W1bf, const uint16_t* __restrict__ W2bf,
                        const float* __restrict__ bp2, const float* __restrict__ Wp2,
                        const float* __restrict__ b_p, const float* __restrict__ bw1g,
                        const float* __restrict__ bw2g, float* __restrict__ out) {
  const int bid = blockIdx.x;
  const int b = bid >> 9, i = bid & 511;
  const int t = threadIdx.x;
  const int wid = t >> 6, l = t & 63;
  const int lm = l & 15, lq = l >> 4;

  __shared__ __align__(16) uint16_t W1l[4096];
  __shared__ __align__(16) uint16_t W2l[4096];
  __shared__ __align__(16) uint16_t H2[4][16][76];
  __shared__ __align__(16) float P0[64];
  __shared__ __align__(16) float a2s[64];
  __shared__ __align__(16) float Pts[3][64];
  __shared__ __align__(16) float comb[4][64][2];
  __shared__ float xps[4][3][64];
  __shared__ float sns[4][2][64];
  __shared__ float msh[12];

  {
    *(bf16x8*)(&W1l[t * 16])     = *(const bf16x8*)(W1bf + t * 16);
    *(bf16x8*)(&W1l[t * 16 + 8]) = *(const bf16x8*)(W1bf + t * 16 + 8);
    *(bf16x8*)(&W2l[t * 16])     = *(const bf16x8*)(W2bf + t * 16);
    *(bf16x8*)(&W2l[t * 16 + 8]) = *(const bf16x8*)(W2bf + t * 16 + 8);
  }

  // ---- phase A: partial sums of the 32 stat-block partials ----
  {
    const int qd = t >> 6, c = t & 63;
    float x0 = 0, x1 = 0, x2 = 0, s0 = 0, s1 = 0;
#pragma unroll
    for (int p = 0; p < 8; ++p) {
      const int blk = qd * 8 + p;
      x0 += XPp[((size_t)blk * 3 + 0) * 64 + c];
      x1 += XPp[((size_t)blk * 3 + 1) * 64 + c];
      x2 += XPp[((size_t)blk * 3 + 2) * 64 + c];
      s0 += SNp[((size_t)blk * 2 + 0) * 64 + c];
      s1 += SNp[((size_t)blk * 2 + 1) * 64 + c];
    }
    xps[qd][0][c] = x0; xps[qd][1][c] = x1; xps[qd][2][c] = x2;
    sns[qd][0][c] = s0; sns[qd][1][c] = s1;
    if (t < 12) {
      float m = 0.f;
#pragma unroll
      for (int p = 0; p < 16; ++p) m += Mpart[p * 12 + t];
      msh[t] = m;
    }
  }
  __syncthreads();

  // ---- assemble a2/be2/Pt per channel ----
  if (t < 64) {
    const int c = t;
    const float URd0 = xps[0][0][c] + xps[1][0][c] + xps[2][0][c] + xps[3][0][c];
    const float URd1 = xps[0][1][c] + xps[1][1][c] + xps[2][1][c] + xps[3][1][c];
    const float URd2 = xps[0][2][c] + xps[1][2][c] + xps[2][2][c] + xps[3][2][c];
    const float Su0 = sns[0][0][c], Su20 = sns[0][1][c];
    const float Su1 = sns[1][0][c], Su21 = sns[1][1][c];
    const float Sk0 = sns[2][0][c], Sk20 = sns[2][1][c];
    const float Sk1 = sns[3][0][c], Sk21 = sns[3][1][c];
    const float P0t = Wp2[c * 3 + 0], P1t = Wp2[c * 3 + 1], P2t = Wp2[c * 3 + 2];
    const float Nf = 512.f, invM = 1.f / 524288.f;
    float S1 = Nf * (Su0 - Sk0) + Nf * (Su1 - Sk1);
    const float Q2 = Nf * Su20 - 2.f * Su0 * Sk0 + Nf * Sk20
                   + Nf * Su21 - 2.f * Su1 * Sk1 + Nf * Sk21;
    const float Xc = P0t * URd0 + P1t * URd1 + P2t * URd2;
    S1 += P0t * msh[6] + P1t * msh[7] + P2t * msh[8];
    const float Hm = P0t * P0t * msh[0] + 2.f * P0t * P1t * msh[1] + 2.f * P0t * P2t * msh[2]
                   + P1t * P1t * msh[3] + 2.f * P1t * P2t * msh[4] + P2t * P2t * msh[5];
    const float E1 = S1 * invM;
    const float E2 = (Q2 + 2.f * Xc + Hm) * invM;
    const float var = E2 - E1 * E1;
    const float A2 = g_w[c] * rsqrtf(var + 1e-5f);
    const float be2 = b_w[c] - E1 * A2;
    a2s[c] = A2;
    P0[c] = fmaf(A2, q[(size_t)(b * 512 + i) * 64 + c] + bp2[c], be2);
    Pts[0][c] = A2 * P0t;
    Pts[1][c] = A2 * P1t;
    Pts[2][c] = A2 * P2t;
  }

  const f32x4 hi = *(const f32x4*)(hpa + (size_t)(b * 512 + i) * 4);
  const float bb0 = b_p[0], bb1 = b_p[1], bb2 = b_p[2];
  const float LOG2E = 1.4426950408889634f;

  float bw1r[4], bw2l[4], wpa[4], wpb[4], wpc[4];
#pragma unroll
  for (int nt = 0; nt < 4; ++nt) {
    const int c = 16 * nt + lm;
    bw1r[nt] = bw1g[c];
    bw2l[nt] = bw2g[c] * LOG2E;
    wpa[nt] = Wp2[c * 3 + 0];
    wpb[nt] = Wp2[c * 3 + 1];
    wpc[nt] = Wp2[c * 3 + 2];
  }

  float l_[4] = {0.f, 0.f, 0.f, 0.f};
  float acc_[4] = {0.f, 0.f, 0.f, 0.f};

  __syncthreads();

  const float* kbase = kk_ + (size_t)(b * 512) * 64;
  const float* hbase = hpa + (size_t)(b * 512) * 4;
  const float* vTb = vT + (size_t)b * 64 * 512;

  // prefetch k-row for it=0
  f32x4 kvA[2][2];
  {
    const int j0 = wid * 16 + lm;
#pragma unroll
    for (int ks = 0; ks < 2; ++ks) {
      kvA[ks][0] = *(const f32x4*)(kbase + (size_t)j0 * 64 + 32 * ks + 8 * lq);
      kvA[ks][1] = *(const f32x4*)(kbase + (size_t)j0 * 64 + 32 * ks + 8 * lq + 4);
    }
  }

  for (int it = 0; it < 8; ++it) {
    const int jb = it * 64 + wid * 16;
    const int j = jb + lm;
    const int j2 = jb + 4 * lq;

    f32x4 kvN[2][2];
    if (it < 7) {
      const int jn = j + 64;
#pragma unroll
      for (int ks = 0; ks < 2; ++ks) {
        kvN[ks][0] = *(const f32x4*)(kbase + (size_t)jn * 64 + 32 * ks + 8 * lq);
        kvN[ks][1] = *(const f32x4*)(kbase + (size_t)jn * 64 + 32 * ks + 8 * lq + 4);
      }
    }

    const f32x4 hj = *(const f32x4*)(hbase + j * 4);
    f32x4 hjr[4];
#pragma unroll
    for (int r = 0; r < 4; ++r) hjr[r] = *(const f32x4*)(hbase + (j2 + r) * 4);
    f32x4 vv[4];
#pragma unroll
    for (int nt = 0; nt < 4; ++nt)
      vv[nt] = *(const f32x4*)(vTb + (size_t)(16 * nt + lm) * 512 + j2);

    const float h0 = fmaxf(0.f, hi.x - hj.x + bb0);
    const float h1 = fmaxf(0.f, hi.y - hj.y + bb1);
    const float h2v = fmaxf(0.f, hi.z - hj.z + bb2);

    FragU A1[2];
#pragma unroll
    for (int ks = 0; ks < 2; ++ks) {
      const int c0 = 32 * ks + 8 * lq;
      f32x4 pv[2], av[2], t0[2], t1[2], t2[2];
      pv[0] = *(const f32x4*)(P0 + c0);        pv[1] = *(const f32x4*)(P0 + c0 + 4);
      av[0] = *(const f32x4*)(a2s + c0);       av[1] = *(const f32x4*)(a2s + c0 + 4);
      t0[0] = *(const f32x4*)(&Pts[0][c0]);    t0[1] = *(const f32x4*)(&Pts[0][c0 + 4]);
      t1[0] = *(const f32x4*)(&Pts[1][c0]);    t1[1] = *(const f32x4*)(&Pts[1][c0 + 4]);
      t2[0] = *(const f32x4*)(&Pts[2][c0]);    t2[1] = *(const f32x4*)(&Pts[2][c0 + 4]);
      float x[8];
#pragma unroll
      for (int e = 0; e < 8; ++e) {
        const int hh = e >> 2, e4 = e & 3;
        float xv = pv[hh][e4] - av[hh][e4] * kvA[ks][hh][e4];
        xv = fmaf(t0[hh][e4], h0, xv);
        xv = fmaf(t1[hh][e4], h1, xv);
        xv = fmaf(t2[hh][e4], h2v, xv);
        x[e] = fmaxf(0.f, xv);
      }
      A1[ks].u[0] = pk_bf16(x[0], x[1]);
      A1[ks].u[1] = pk_bf16(x[2], x[3]);
      A1[ks].u[2] = pk_bf16(x[4], x[5]);
      A1[ks].u[3] = pk_bf16(x[6], x[7]);
    }

    f32x4 d1[4];
#pragma unroll
    for (int nt = 0; nt < 4; ++nt) {
      FragU b0, b1;
      b0.f = *(const bf16x8*)(&W1l[((nt * 2 + 0) * 64 + l) * 8]);
      b1.f = *(const bf16x8*)(&W1l[((nt * 2 + 1) * 64 + l) * 8]);
      f32x4 z = {bw1r[nt], bw1r[nt], bw1r[nt], bw1r[nt]};
      z = __builtin_amdgcn_mfma_f32_16x16x32_bf16(A1[0].f, b0.f, z, 0, 0, 0);
      z = __builtin_amdgcn_mfma_f32_16x16x32_bf16(A1[1].f, b1.f, z, 0, 0, 0);
      d1[nt] = z;
    }

    uint16_t (*h2w)[76] = H2[wid];
#pragma unroll
    for (int nt = 0; nt < 4; ++nt) {
      const uint32_t u01 = pk_bf16(fmaxf(0.f, d1[nt][0]), fmaxf(0.f, d1[nt][1]));
      const uint32_t u23 = pk_bf16(fmaxf(0.f, d1[nt][2]), fmaxf(0.f, d1[nt][3]));
      const int col = 16 * nt + lm;
      h2w[4 * lq + 0][col] = (uint16_t)(u01 & 0xffffu);
      h2w[4 * lq + 1][col] = (uint16_t)(u01 >> 16);
      h2w[4 * lq + 2][col] = (uint16_t)(u23 & 0xffffu);
      h2w[4 * lq + 3][col] = (uint16_t)(u23 >> 16);
    }

    FragU A2[2];
    A2[0].f = *(const bf16x8*)(&h2w[lm][8 * lq]);
    A2[1].f = *(const bf16x8*)(&h2w[lm][32 + 8 * lq]);

    f32x4 d2[4];
#pragma unroll
    for (int nt = 0; nt < 4; ++nt) {
      FragU b0, b1;
      b0.f = *(const bf16x8*)(&W2l[((nt * 2 + 0) * 64 + l) * 8]);
      b1.f = *(const bf16x8*)(&W2l[((nt * 2 + 1) * 64 + l) * 8]);
      f32x4 z = {bw2l[nt], bw2l[nt], bw2l[nt], bw2l[nt]};
      z = __builtin_amdgcn_mfma_f32_16x16x32_bf16(A2[0].f, b0.f, z, 0, 0, 0);
      z = __builtin_amdgcn_mfma_f32_16x16x32_bf16(A2[1].f, b1.f, z, 0, 0, 0);
      d2[nt] = z;
    }

    float hr0[4], hr1[4], hr2[4];
#pragma unroll
    for (int r = 0; r < 4; ++r) {
      hr0[r] = fmaxf(0.f, hi.x - hjr[r].x + bb0);
      hr1[r] = fmaxf(0.f, hi.y - hjr[r].y + bb1);
      hr2[r] = fmaxf(0.f, hi.z - hjr[r].z + bb2);
    }

#pragma unroll
    for (int nt = 0; nt < 4; ++nt) {
      float p[4], val[4];
#pragma unroll
      for (int r = 0; r < 4; ++r) {
        p[r] = __builtin_amdgcn_exp2f(d2[nt][r]);
        float v0 = vv[nt][r];
        v0 = fmaf(wpa[nt], hr0[r], v0);
        v0 = fmaf(wpb[nt], hr1[r], v0);
        v0 = fmaf(wpc[nt], hr2[r], v0);
        val[r] = v0;
      }
      l_[nt] += (p[0] + p[1]) + (p[2] + p[3]);
      float a = acc_[nt];
      a = fmaf(p[0], val[0], a);
      a = fmaf(p[1], val[1], a);
      a = fmaf(p[2], val[2], a);
      a = fmaf(p[3], val[3], a);
      acc_[nt] = a;
    }

    if (it < 7) {
#pragma unroll
      for (int ks = 0; ks < 2; ++ks) {
        kvA[ks][0] = kvN[ks][0];
        kvA[ks][1] = kvN[ks][1];
      }
    }
  }

#pragma unroll
  for (int nt = 0; nt < 4; ++nt) {
    l_[nt] += __shfl_xor(l_[nt], 16);
    acc_[nt] += __shfl_xor(acc_[nt], 16);
    l_[nt] += __shfl_xor(l_[nt], 32);
    acc_[nt] += __shfl_xor(acc_[nt], 32);
  }
  if (lq == 0) {
#pragma unroll
    for (int nt = 0; nt < 4; ++nt) {
      comb[wid][16 * nt + lm][0] = l_[nt];
      comb[wid][16 * nt + lm][1] = acc_[nt];
    }
  }
  __syncthreads();
  if (t < 64) {
    float L = 0.f, A = 0.f;
#pragma unroll
    for (int w = 0; w < 4; ++w) {
      L += comb[w][t][0];
      A += comb[w][t][1];
    }
    out[(size_t)(b * 512 + i) * 64 + t] = A / L;
  }
}

// ---------------------------------------------------------------------------
extern "C" void kernel_launch(void* const* d_in, const int* in_sizes, int n_in,
                              void* d_out, int out_size, void* d_ws, size_t ws_size,
                              hipStream_t stream) {
  (void)in_sizes; (void)n_in; (void)out_size; (void)ws_size;
  const float* pos = (const float*)d_in[0];
  const float* cf  = (const float*)d_in[1];
  const float* Wq  = (const float*)d_in[2];
  const float* bq  = (const float*)d_in[3];
  const float* Wk  = (const float*)d_in[4];
  const float* bk  = (const float*)d_in[5];
  const float* Wv  = (const float*)d_in[6];
  const float* bv  = (const float*)d_in[7];
  const float* Wp1 = (const float*)d_in[8];
  // d_in[9] = bp1: cancels analytically (gamma1 == b_p exactly)
  const float* g_p = (const float*)d_in[10];
  const float* b_p = (const float*)d_in[11];
  const float* Wp2 = (const float*)d_in[12];
  const float* bp2 = (const float*)d_in[13];
  const float* g_w = (const float*)d_in[14];
  const float* b_w = (const float*)d_in[15];
  const float* Ww1 = (const float*)d_in[16];
  const float* bw1 = (const float*)d_in[17];
  const float* Ww2 = (const float*)d_in[18];
  const float* bw2 = (const float*)d_in[19];

  char* ws = (char*)d_ws;
  uint16_t* W1bf = (uint16_t*)(ws + 0);        // 8 KB
  uint16_t* W2bf = (uint16_t*)(ws + 8192);     // 8 KB (log2e-scaled)
  float*    hpaw = (float*)(ws + 16896);       // [1024][4]
  float*    qw   = (float*)(ws + 33280);       // [1024][64]
  float*    kw   = (float*)(ws + 295424);      // [1024][64]
  float*    vTw  = (float*)(ws + 557568);      // [2][64][512]
  float*    Mpw  = (float*)(ws + 821248);      // [32][12]
  float*    XPpw = (float*)(ws + 823040);      // [32][3][64]
  float*    SNpw = (float*)(ws + 847872);      // [32][2][64]

  kAll<<<dim3(161), dim3(256), 0, stream>>>(cf, pos, Wq, Wk, Wv, bq, bk, bv,
                                            Ww1, Ww2, Wp1, g_p, b_p, bp2,
                                            qw, kw, vTw, W1bf, W2bf, hpaw,
                                            Mpw, XPpw, SNpw);
  k3_main<<<dim3(1024), dim3(256), 0, stream>>>(qw, kw, vTw, hpaw, Mpw, XPpw, SNpw,
                                                g_w, b_w, W1bf, W2bf, bp2, Wp2, b_p,
                                                bw1, bw2, (float*)d_out);
}